// Round 10
// baseline (889.863 us; speedup 1.0000x reference)
//
#include <hip/hip_runtime.h>
#include <cstdio>

// Qwen2 MoE sparse block, MI355X gfx950.
// Round 10: R9 GEMM core verbatim (best, 775us). New: "dispatch stuffing" --
// weight conversions run as trailing jobs inside the preceding GEMM dispatch
// (GEMM blocks first, fine-grained cvt jobs backfill idle CUs); sh-down and
// e-down fused into one packed dispatch; cvt_x merged into router.

#define H_DIM 2048
#define IMOE  1408
#define ISH   5632
#define NEXP  8
#define T_TOK 2048
#define TK_TOT (T_TOK * 2)

typedef __attribute__((ext_vector_type(8))) short short8;
typedef __attribute__((ext_vector_type(8))) __bf16 bf16x8;
typedef __attribute__((ext_vector_type(4))) float f32x4;

__device__ __forceinline__ float bf2f(unsigned short u) {
  union { unsigned int i; float f; } v; v.i = ((unsigned int)u) << 16; return v.f;
}
__device__ __forceinline__ unsigned short f2bf(float f) {
  union { float f; unsigned int i; } v; v.f = f;
  unsigned int x = v.i;
  return (unsigned short)((x + 0x7fffu + ((x >> 16) & 1u)) >> 16);
}

__device__ __forceinline__ f32x4 MFMA16(short8 a, short8 b, f32x4 c) {
  return __builtin_amdgcn_mfma_f32_16x16x32_bf16(
      __builtin_bit_cast(bf16x8, a), __builtin_bit_cast(bf16x8, b), c, 0, 0, 0);
}

__device__ __forceinline__ void gload_lds16(const unsigned short* g, unsigned short* l) {
  __builtin_amdgcn_global_load_lds(
      (const __attribute__((address_space(1))) unsigned int*)g,
      (__attribute__((address_space(3))) unsigned int*)l, 16, 0, 0);
}

__device__ __forceinline__ float silu_f(float x) { return x / (1.0f + __expf(-x)); }

#define SBAR()   asm volatile("s_barrier" ::: "memory")
#define VMCNT(n) asm volatile("s_waitcnt vmcnt(" #n ")" ::: "memory")

// ---------------- GEMM core (R9 verbatim, block coords as args) ----------------
// C[M,N] = A[M,K](bf16) * BT[N,K]^T(bf16). 512 thr = 8 waves (2Mx4N), wave
// tile 128x64, BK=64, 2 LDS buffers (128 KiB). 16B-granule XOR swizzle.
// EPI: 1 = unsafeAtomicAdd f32 * rowscale; 2 = f32 store; 3 = silu-pair bf16.
template <int EPI, bool EXPERT>
__device__ __forceinline__ void gemm_core(
    const unsigned short* __restrict__ A, const unsigned short* __restrict__ BT,
    void* __restrict__ Cv, int N, int Kld, int KLEN, int M,
    const int* __restrict__ counts, const int* __restrict__ offsets,
    const float* __restrict__ rowscale, long bt_estride,
    int bx, int by, int bz, unsigned short* lds8) {
  int cnt = M, rowbase = 0, k0 = 0;
  const unsigned short* bt = BT;
  if constexpr (EXPERT) {
    cnt = counts[bz];
    rowbase = offsets[bz];
    bt += (long)bz * bt_estride;
  } else {
    k0 = bz * KLEN;
  }
  int row0 = bx * 256;
  if (row0 >= cnt) return;
  int col0 = by * 256;

  int tid = threadIdx.x, wave = tid >> 6, lane = tid & 63;
  int NT = KLEN / 64;

  const unsigned short* aSrc[4];
  const unsigned short* bSrc[4];
#pragma unroll
  for (int s = 0; s < 4; s++) {
    int r = s * 64 + (tid >> 3);
    int g = (tid & 7) ^ (r & 7);
    long ar = row0 + r;
    if (ar > cnt - 1) ar = cnt - 1;
    ar += rowbase;
    aSrc[s] = A + ar * (long)Kld + k0 + g * 8;
    bSrc[s] = bt + (long)(col0 + r) * Kld + k0 + g * 8;
  }

  int wr = wave >> 2, wc = wave & 3;
  int fr = lane & 15, fg = lane >> 4;
  int aOff[8][2], bOff[4][2];
#pragma unroll
  for (int ks = 0; ks < 2; ks++) {
    int q = ((ks * 4 + fg) ^ (fr & 7)) * 8;
#pragma unroll
    for (int m = 0; m < 8; m++) aOff[m][ks] = (wr * 128 + m * 16 + fr) * 64 + q;
#pragma unroll
    for (int n = 0; n < 4; n++) bOff[n][ks] = (wc * 64 + n * 16 + fr) * 64 + q;
  }

#define STAGE(p, t) do { long kk = (long)(t) * 64; \
    _Pragma("unroll") for (int s = 0; s < 4; s++) { \
      gload_lds16(aSrc[s] + kk, &lds8[(p) * 16384 + s * 4096 + wave * 512]); \
      gload_lds16(bSrc[s] + kk, &lds8[32768 + (p) * 16384 + s * 4096 + wave * 512]); \
    } } while (0)

  f32x4 acc[8][4] = {};

  STAGE(0, 0);
  VMCNT(0);
  SBAR();

  for (int t = 0; t < NT; t++) {
    int p = t & 1;
    if (t + 1 < NT) STAGE(p ^ 1, t + 1);
#pragma unroll
    for (int ks = 0; ks < 2; ks++) {
      short8 aF[8], bF[4];
#pragma unroll
      for (int m = 0; m < 8; m++) aF[m] = *(const short8*)&lds8[p * 16384 + aOff[m][ks]];
#pragma unroll
      for (int n = 0; n < 4; n++) bF[n] = *(const short8*)&lds8[32768 + p * 16384 + bOff[n][ks]];
      __builtin_amdgcn_s_setprio(1);
#pragma unroll
      for (int m = 0; m < 8; m++)
#pragma unroll
        for (int n = 0; n < 4; n++)
          acc[m][n] = MFMA16(aF[m], bF[n], acc[m][n]);
      __builtin_amdgcn_s_setprio(0);
    }
    VMCNT(0);
    SBAR();
  }

  int rowguard = cnt - row0;
#pragma unroll
  for (int m = 0; m < 8; m++) {
    int rl = wr * 128 + m * 16 + fg * 4;
#pragma unroll
    for (int n = 0; n < 4; n++) {
      int cg = col0 + wc * 64 + n * 16 + fr;
      f32x4 v = acc[m][n];
#pragma unroll
      for (int j = 0; j < 4; j++) {
        int r = rl + j;
        float pv = __shfl_xor(v[j], 1);
        if (r < rowguard) {
          long orow = (long)rowbase + row0 + r;
          if constexpr (EPI == 1) {
            unsafeAtomicAdd(&((float*)Cv)[orow * (long)N + cg], v[j] * rowscale[orow]);
          } else if constexpr (EPI == 2) {
            ((float*)Cv)[orow * (long)N + cg] = v[j];
          } else {
            if (!(fr & 1)) {
              float hval = silu_f(v[j]) * pv;
              ((unsigned short*)Cv)[orow * (long)(N >> 1) + (cg >> 1)] = f2bf(hval);
            }
          }
        }
      }
    }
  }
#undef STAGE
}

// ---------------- cvt job (512 threads, 64 32x32-tiles per job) ----------------
// fp32 [Y][Cc] (z-batched) -> bf16 [C'][Y]; ILV if I>0.
__device__ __forceinline__ void cvt_job(
    const float* __restrict__ src, unsigned short* __restrict__ dst, int j,
    int Ytiles, int Ctiles, int Cc, int Rr, int I, long sStride, long dStride,
    void* ldsraw) {
  float (*tile)[33] = (float(*)[33])ldsraw;
  int tid = threadIdx.x;
  int tx = tid & 31, ty = tid >> 5;   // ty 0..15
  int perz = Ytiles * Ctiles;
  for (int it = 0; it < 64; ++it) {
    int tl = j * 64 + it;
    int tz = tl / perz, rem = tl - tz * perz;
    int tyc = rem / Ctiles, txc = rem - tyc * Ctiles;
    const float* s = src + (long)tz * sStride;
    unsigned short* d = dst + (long)tz * dStride;
    int yb = tyc * 32, x0 = txc * 32;
    __syncthreads();
#pragma unroll
    for (int jj = 0; jj < 2; jj++) {
      int y = ty + jj * 16;
      tile[y][tx] = s[(long)(yb + y) * Cc + x0 + tx];
    }
    __syncthreads();
#pragma unroll
    for (int jj = 0; jj < 2; jj++) {
      int c = x0 + ty + jj * 16;
      int cd = I ? (c < I ? 2 * c : 2 * (c - I) + 1) : c;
      d[(long)cd * Rr + yb + tx] = f2bf(tile[tx][ty + jj * 16]);
    }
  }
}

// ---------------- standalone cvt (dispatch A: Wsgu) ----------------
template <bool ILV>
__global__ __launch_bounds__(256)
void transpose_cvt_kernel(const float* __restrict__ src, unsigned short* __restrict__ dst,
                          int R, int C, int I) {
  __shared__ float tile[32][33];
  int tx = threadIdx.x, ty = threadIdx.y;           // 32 x 8
  int x = blockIdx.x * 32 + tx;
  int yb = blockIdx.y * 32;
#pragma unroll
  for (int j = 0; j < 4; j++) {
    int y = yb + ty + j * 8;
    tile[ty + j * 8][tx] = src[(long)y * C + x];
  }
  __syncthreads();
  int r = yb + tx;
#pragma unroll
  for (int j = 0; j < 4; j++) {
    int c = blockIdx.x * 32 + ty + j * 8;
    int cd = ILV ? (c < I ? 2 * c : 2 * (c - I) + 1) : c;
    dst[(long)cd * R + r] = f2bf(tile[tx][ty + j * 8]);
  }
}

// ---------------- routing (+ x -> bf16) ----------------

__global__ __launch_bounds__(256)
void router_kernel(const float* __restrict__ x, const float* __restrict__ Wr,
                   const float* __restrict__ Wsg, float* __restrict__ rw,
                   int* __restrict__ sel, float* __restrict__ sgate_sig,
                   int* __restrict__ counts, unsigned short* __restrict__ xbf) {
  int t = blockIdx.x;
  const float* xr = x + (long)t * H_DIM;
  unsigned short* xo = xbf + (long)t * H_DIM;
  float p[9];
#pragma unroll
  for (int e = 0; e < 9; e++) p[e] = 0.0f;
  for (int h = threadIdx.x; h < H_DIM; h += 256) {
    float xv = xr[h];
    xo[h] = f2bf(xv);
#pragma unroll
    for (int e = 0; e < 8; e++) p[e] += xv * Wr[e * H_DIM + h];
    p[8] += xv * Wsg[h];
  }
#pragma unroll
  for (int e = 0; e < 9; e++)
    for (int off = 32; off > 0; off >>= 1)
      p[e] += __shfl_down(p[e], off, 64);
  __shared__ float red[4][9];
  int wave = threadIdx.x >> 6, lane = threadIdx.x & 63;
  if (lane == 0) {
#pragma unroll
    for (int e = 0; e < 9; e++) red[wave][e] = p[e];
  }
  __syncthreads();
  if (threadIdx.x == 0) {
    float lg[9];
#pragma unroll
    for (int e = 0; e < 9; e++) lg[e] = red[0][e] + red[1][e] + red[2][e] + red[3][e];
    float m = lg[0];
#pragma unroll
    for (int e = 1; e < 8; e++) m = fmaxf(m, lg[e]);
    float pr[8], s = 0.0f;
#pragma unroll
    for (int e = 0; e < 8; e++) { pr[e] = expf(lg[e] - m); s += pr[e]; }
    float inv = 1.0f / s;
#pragma unroll
    for (int e = 0; e < 8; e++) pr[e] *= inv;
    int i0 = 0;
#pragma unroll
    for (int e = 1; e < 8; e++) if (pr[e] > pr[i0]) i0 = e;
    int i1 = (i0 == 0) ? 1 : 0;
#pragma unroll
    for (int e = 0; e < 8; e++) if (e != i0 && pr[e] > pr[i1]) i1 = e;
    rw[t * 2] = pr[i0]; rw[t * 2 + 1] = pr[i1];
    sel[t * 2] = i0;    sel[t * 2 + 1] = i1;
    sgate_sig[t] = 1.0f / (1.0f + expf(-lg[8]));
    atomicAdd(&counts[i0], 1);
    atomicAdd(&counts[i1], 1);
  }
}

__global__ void scan_kernel(const int* __restrict__ counts, int* __restrict__ offsets) {
  if (threadIdx.x == 0 && blockIdx.x == 0) {
    int s = 0;
    for (int e = 0; e < NEXP; e++) { offsets[e] = s; s += counts[e]; }
    offsets[NEXP] = s;
  }
}

__global__ __launch_bounds__(256)
void scatter_kernel(const int* __restrict__ sel, const int* __restrict__ offsets,
                    int* __restrict__ cursor, int* __restrict__ tok_of_slot,
                    int* __restrict__ slot_of_tok) {
  int t = blockIdx.x * 256 + threadIdx.x;
  if (t >= T_TOK) return;
#pragma unroll
  for (int k = 0; k < 2; k++) {
    int e = sel[t * 2 + k];
    int pos = atomicAdd(&cursor[e], 1);
    int slot = offsets[e] + pos;
    tok_of_slot[slot] = t;
    slot_of_tok[t * 2 + k] = slot;
  }
}

__global__ __launch_bounds__(256)
void gather_kernel(const unsigned short* __restrict__ xbf, const int* __restrict__ tok,
                   unsigned short* __restrict__ xg) {
  int i = blockIdx.x * 256 + threadIdx.x;
  int slot = i >> 8, c8 = i & 255;
  long src = (long)tok[slot] * H_DIM + c8 * 8;
  ulonglong2 v = *(const ulonglong2*)(xbf + src);
  ((ulonglong2*)xg)[i] = v;
}

// ---------------- stuffed dispatches ----------------

// B: [0,352) sh-gu GEMM (8r x 44c); [352,1056) cvt Wegu (704 jobs);
//    [1056,1232) cvt Wsd (176 jobs)
__global__ __launch_bounds__(512, 2)
void megaB_kernel(const unsigned short* __restrict__ xbf,
                  const unsigned short* __restrict__ WsguT,
                  unsigned short* __restrict__ h_sh,
                  const float* __restrict__ Wegu, unsigned short* __restrict__ WeguT,
                  const float* __restrict__ Wsd, unsigned short* __restrict__ WsdT) {
  __shared__ unsigned short lds8[65536];
  int b = blockIdx.x;
  if (b < 352) {
    int s = (b & 7) * 44 + (b >> 3);            // XCD swizzle within GEMM region
    gemm_core<3, false>(xbf, WsguT, h_sh, 2 * ISH, H_DIM, H_DIM, T_TOK,
                        nullptr, nullptr, nullptr, 0, s % 8, s / 8, 0, lds8);
  } else if (b < 1056) {
    cvt_job(Wegu, WeguT, b - 352, 64, 88, 2 * IMOE, H_DIM, IMOE,
            (long)H_DIM * 2 * IMOE, (long)2 * IMOE * H_DIM, lds8);
  } else {
    cvt_job(Wsd, WsdT, b - 1056, 176, 64, H_DIM, ISH, 0, 0, 0, lds8);
  }
}

// C: [0,704) e-gu GEMM (8e x 11c x 8r, early-return); [704,1056) cvt Wed (352)
__global__ __launch_bounds__(512, 2)
void megaC_kernel(const unsigned short* __restrict__ xg,
                  const unsigned short* __restrict__ WeguT,
                  unsigned short* __restrict__ h_e,
                  const int* __restrict__ counts, const int* __restrict__ offsets,
                  const float* __restrict__ Wed, unsigned short* __restrict__ WedT) {
  __shared__ unsigned short lds8[65536];
  int b = blockIdx.x;
  if (b < 704) {
    int s = (b & 7) * 88 + (b >> 3);
    int e = s / 88, r2 = s % 88;
    gemm_core<3, true>(xg, WeguT, h_e, 2 * IMOE, H_DIM, H_DIM, 0,
                       counts, offsets, nullptr, (long)2 * IMOE * H_DIM,
                       r2 % 8, r2 / 8, e, lds8);
  } else {
    cvt_job(Wed, WedT, b - 704, 44, 64, H_DIM, IMOE,
            0, (long)IMOE * H_DIM, (long)H_DIM * IMOE, lds8);
  }
}

// D: [0,256) sh-down splitK4 atomic; [256,768) e-down (8e x 8c x 8r)
__global__ __launch_bounds__(512, 2)
void megaD_kernel(const unsigned short* __restrict__ h_sh,
                  const unsigned short* __restrict__ WsdT,
                  float* __restrict__ out, const float* __restrict__ sgate,
                  const unsigned short* __restrict__ h_e,
                  const unsigned short* __restrict__ WedT,
                  float* __restrict__ eo,
                  const int* __restrict__ counts, const int* __restrict__ offsets) {
  __shared__ unsigned short lds8[65536];
  int o = blockIdx.x;
  int s = (o & 7) * 96 + (o >> 3);              // swizzle across all 768
  if (s < 256) {
    gemm_core<1, false>(h_sh, WsdT, out, H_DIM, ISH, ISH / 4, T_TOK,
                        nullptr, nullptr, sgate, 0,
                        s % 8, (s >> 3) & 7, s >> 6, lds8);
  } else {
    int s2 = s - 256;
    int e = s2 >> 6, r2 = s2 & 63;
    gemm_core<2, true>(h_e, WedT, eo, H_DIM, IMOE, IMOE, 0,
                       counts, offsets, nullptr, (long)H_DIM * IMOE,
                       r2 % 8, r2 / 8, e, lds8);
  }
}

// ---------------- combine ----------------

__global__ __launch_bounds__(256)
void combine_kernel(float* __restrict__ out, const float* __restrict__ eo,
                    const int* __restrict__ slot_of_tok, const float* __restrict__ rw) {
  int i = blockIdx.x * 256 + threadIdx.x;
  const int h4n = H_DIM / 4;
  if (i >= T_TOK * h4n) return;
  int t = i / h4n;
  int h4 = i - t * h4n;
  int s0 = slot_of_tok[t * 2], s1 = slot_of_tok[t * 2 + 1];
  float w0 = rw[t * 2], w1 = rw[t * 2 + 1];
  float4 o = ((float4*)out)[i];
  float4 a = ((const float4*)eo)[(long)s0 * h4n + h4];
  float4 b = ((const float4*)eo)[(long)s1 * h4n + h4];
  o.x += w0 * a.x + w1 * b.x;
  o.y += w0 * a.y + w1 * b.y;
  o.z += w0 * a.z + w1 * b.z;
  o.w += w0 * a.w + w1 * b.w;
  ((float4*)out)[i] = o;
}

// ---------------- host ----------------

extern "C" void kernel_launch(void* const* d_in, const int* in_sizes, int n_in,
                              void* d_out, int out_size, void* d_ws, size_t ws_size,
                              hipStream_t stream) {
  (void)in_sizes; (void)n_in; (void)out_size;
  const float* x    = (const float*)d_in[0];
  const float* Wr   = (const float*)d_in[1];
  const float* Wsg  = (const float*)d_in[2];
  const float* Wsgu = (const float*)d_in[3];
  const float* Wsd  = (const float*)d_in[4];
  const float* Wegu = (const float*)d_in[5];
  const float* Wed  = (const float*)d_in[6];
  float* out = (float*)d_out;

  char* ws = (char*)d_ws;
  size_t off = 0;
  auto alloc = [&](size_t b) { size_t o = off; off += (b + 255) & ~(size_t)255; return o; };

  size_t o_xbf   = alloc((size_t)T_TOK * H_DIM * 2);
  size_t o_WsguT = alloc((size_t)2 * ISH * H_DIM * 2);          // aliased as eo later
  size_t o_WsdT  = alloc((size_t)H_DIM * ISH * 2);
  size_t o_WeguT = alloc((size_t)NEXP * 2 * IMOE * H_DIM * 2);
  size_t o_WedT  = alloc((size_t)NEXP * H_DIM * IMOE * 2);
  size_t o_hsh   = alloc((size_t)T_TOK * ISH * 2);
  size_t o_he    = alloc((size_t)TK_TOT * IMOE * 2);
  size_t o_xg    = alloc((size_t)TK_TOT * H_DIM * 2);
  size_t o_ints  = alloc(256);
  size_t o_rw    = alloc((size_t)TK_TOT * 4);
  size_t o_sel   = alloc((size_t)TK_TOT * 4);
  size_t o_sg    = alloc((size_t)T_TOK * 4);
  size_t o_tok   = alloc((size_t)TK_TOT * 4);
  size_t o_s2t   = alloc((size_t)TK_TOT * 4);

  if (off > ws_size) {
    fprintf(stderr, "[moe kernel] workspace too small: need %zu have %zu\n", off, ws_size);
    return;
  }

  unsigned short* xbf   = (unsigned short*)(ws + o_xbf);
  unsigned short* WsguT = (unsigned short*)(ws + o_WsguT);
  unsigned short* WsdT  = (unsigned short*)(ws + o_WsdT);
  unsigned short* WeguT = (unsigned short*)(ws + o_WeguT);
  unsigned short* WedT  = (unsigned short*)(ws + o_WedT);
  unsigned short* h_sh  = (unsigned short*)(ws + o_hsh);
  unsigned short* h_e   = (unsigned short*)(ws + o_he);
  unsigned short* xg    = (unsigned short*)(ws + o_xg);
  float* eo             = (float*)(ws + o_WsguT);   // alias: WsguT dead after megaB

  int* ints    = (int*)(ws + o_ints);
  int* counts  = ints;
  int* cursor  = ints + 8;
  int* offsets = ints + 16;
  float* rw    = (float*)(ws + o_rw);
  int* sel     = (int*)(ws + o_sel);
  float* sgate = (float*)(ws + o_sg);
  int* tok     = (int*)(ws + o_tok);
  int* s2t     = (int*)(ws + o_s2t);

  hipMemsetAsync(ints, 0, 64, stream);
  hipMemsetAsync(out, 0, (size_t)T_TOK * H_DIM * 4, stream);   // atomic target

  // A: standalone conversion of Wsgu (consumer is the very next GEMM)
  transpose_cvt_kernel<true><<<dim3(2 * ISH / 32, H_DIM / 32, 1), dim3(32, 8, 1), 0, stream>>>(
      Wsgu, WsguT, H_DIM, 2 * ISH, ISH);

  // prep (router also produces xbf)
  router_kernel<<<T_TOK, 256, 0, stream>>>(x, Wr, Wsg, rw, sel, sgate, counts, xbf);
  scan_kernel<<<1, 64, 0, stream>>>(counts, offsets);
  scatter_kernel<<<(T_TOK + 255) / 256, 256, 0, stream>>>(sel, offsets, cursor, tok, s2t);
  gather_kernel<<<TK_TOT, 256, 0, stream>>>(xbf, tok, xg);

  // B: sh-gu GEMM (+fused silu) -> h_sh  ||  cvt Wegu + cvt Wsd (stuffed)
  megaB_kernel<<<1232, 512, 0, stream>>>(xbf, WsguT, h_sh, Wegu, WeguT, Wsd, WsdT);

  // C: e-gu GEMM (+fused silu) -> h_e  ||  cvt Wed (stuffed)
  megaC_kernel<<<1056, 512, 0, stream>>>(xg, WeguT, h_e, counts, offsets, Wed, WedT);

  // D: sh-down splitK4 atomic -> out  +  e-down -> eo (fused, packed)
  megaD_kernel<<<768, 512, 0, stream>>>(h_sh, WsdT, out, sgate, h_e, WedT, eo,
                                        counts, offsets);

  combine_kernel<<<(T_TOK * H_DIM / 4) / 256, 256, 0, stream>>>(out, eo, s2t, rw);
}